// Round 5
// baseline (231.950 us; speedup 1.0000x reference)
//
#include <hip/hip_runtime.h>

typedef float v2f __attribute__((ext_vector_type(2)));
typedef float v4f __attribute__((ext_vector_type(4)));

#define DD   187   // input dim
#define HH   50    // hidden
#define PH   64    // LDS padded hidden (4 lanes x 16 slots)
#define HPJ  14    // hidden neurons per lane (logical)
#define HPL  16    // LDS slots per lane (64B -> b128-aligned reads)
#define NP   7     // float2 pairs per lane
#define NC   5     // classes
#define RPB  64    // rows per block (4 lanes/row, 256 threads)
#define BLK  256
#define DCH  64    // d-chunk
#define NCHUNK 3   // ceil(187/64)
#define XSS  68    // xs row stride (mult of 4 -> 16B-aligned v4f reads)
#define BETA 0.9f

// ---- forced packed f32 math. gfx950 VOP3P f32 set is ONLY pk_fma/pk_mul/pk_add
// (v_pk_min/max_f32 do NOT exist -> round-4 compile fail). Clamp uses the
// v_med3_f32 idiom per half instead. Non-volatile asm: pure, schedulable.
__device__ __forceinline__ v2f pk_fma(v2f a, v2f b, v2f c) {
    v2f d;
    asm("v_pk_fma_f32 %0, %1, %2, %3" : "=v"(d) : "v"(a), "v"(b), "v"(c));
    return d;
}

__device__ __forceinline__ float dpp_xor1(float v) {
    // quad_perm [1,0,3,2] -> lane^1
    return __builtin_bit_cast(float,
        __builtin_amdgcn_mov_dpp(__builtin_bit_cast(int, v), 0xB1, 0xF, 0xF, true));
}
__device__ __forceinline__ float dpp_xor2(float v) {
    // quad_perm [2,3,0,1] -> lane^2
    return __builtin_bit_cast(float,
        __builtin_amdgcn_mov_dpp(__builtin_bit_cast(int, v), 0x4E, 0xF, 0xF, true));
}

__device__ __forceinline__ float spike1(float m) {
    // exact (m > 1) ? 1 : 0 : fma(m,2^60,-2^60) > 0 iff m>1 (f32), med3-clamp to [0,1]
    float t = fmaf(m, 0x1.0p60f, -0x1.0p60f);
    return __builtin_amdgcn_fmed3f(t, 0.f, 1.f);
}

__device__ __forceinline__ v2f vlo(v4f v) { return __builtin_shufflevector(v, v, 0, 1); }
__device__ __forceinline__ v2f vhi(v4f v) { return __builtin_shufflevector(v, v, 2, 3); }

// Structural occupancy is 2 waves/SIMD (2048 waves / 1024 SIMDs) -> register budget
// is 256/wave. launch_bounds 2nd arg = min waves per EU (NOT workgroups/CU).
__global__ __launch_bounds__(BLK, 2) __attribute__((amdgpu_waves_per_eu(2, 2)))
void snn_kernel(const float* __restrict__ x,
                const float* __restrict__ W1,
                const float* __restrict__ b1,
                const float* __restrict__ W2,
                const float* __restrict__ b2,
                const int*   __restrict__ nsp,
                float* __restrict__ out, int Brows)
{
    __shared__ __align__(16) float xs[RPB * XSS];   // 17,408 B
    __shared__ __align__(16) float w1t[DCH * PH];   // 16,384 B (d-major, 4x16 slots)

    const int tid = threadIdx.x;
    const int p   = tid >> 2;         // row within block (quad id)
    const int k   = tid & 3;          // lane within quad: hidden slice + class owner
    const int row = blockIdx.x * RPB + p;
    const int NS  = nsp[0];

    // packed constants (VGPR pairs, loop-invariant)
    const v2f BETA2 = {BETA, BETA};
    const v2f MONE2 = {-1.f, -1.f};
    const v2f BIG2  = { 0x1.0p60f,  0x1.0p60f};
    const v2f NBIG2 = {-0x1.0p60f, -0x1.0p60f};
    const v2f ZERO2 = {0.f, 0.f};

    // ---------------- Phase 1: cur1 = x @ W1^T (chunked over d) ----------------
    v2f acc[NP];
#pragma unroll
    for (int i = 0; i < NP; ++i) acc[i] = (v2f){0.f, 0.f};

    for (int ch = 0; ch < NCHUNK; ++ch) {
        const int d0 = ch * DCH;
        for (int i = tid; i < RPB * DCH; i += BLK) {
            int r = i >> 6, dd = i & 63;
            int d = d0 + dd;
            xs[r * XSS + dd] = (d < DD) ? x[(size_t)(blockIdx.x * RPB + r) * DD + d] : 0.f;
        }
        // conflict-free staging: consecutive threads -> consecutive LDS addresses.
        // slot s = kk*16 + j holds logical hidden h = kk*14 + j (j<14), pads zero.
        for (int i = tid; i < DCH * PH; i += BLK) {
            int dd = i >> 6, s = i & 63;
            int kk = s >> 4, j = s & 15;
            int h = kk * HPJ + j;
            int d = d0 + dd;
            w1t[dd * PH + s] = (j < HPJ && h < HH && d < DD) ? W1[h * DD + d] : 0.f;
        }
        __syncthreads();

        const float* xr = xs + p * XSS;
#pragma unroll 2
        for (int d4 = 0; d4 < DCH / 4; ++d4) {
            v4f xv4 = *(const v4f*)(xr + 4 * d4);
#pragma unroll
            for (int j = 0; j < 4; ++j) {
                int d = 4 * d4 + j;
                const float* wbase = w1t + d * PH + k * HPL;   // 64B aligned per lane
                v4f w0 = *(const v4f*)(wbase);
                v4f w1v = *(const v4f*)(wbase + 4);
                v4f w2v = *(const v4f*)(wbase + 8);
                v2f w3 = *(const v2f*)(wbase + 12);            // pairs (12,13)
                float xv = xv4[j];
                v2f xvv = {xv, xv};
                acc[0] = pk_fma(xvv, vlo(w0),  acc[0]);
                acc[1] = pk_fma(xvv, vhi(w0),  acc[1]);
                acc[2] = pk_fma(xvv, vlo(w1v), acc[2]);
                acc[3] = pk_fma(xvv, vhi(w1v), acc[3]);
                acc[4] = pk_fma(xvv, vlo(w2v), acc[4]);
                acc[5] = pk_fma(xvv, vhi(w2v), acc[5]);
                acc[6] = pk_fma(xvv, w3,       acc[6]);
            }
        }
        __syncthreads();
    }

    // cur1 = acc + b1 (pads stay 0 -> padded neurons never spike)
    v2f c1[NP];
#pragma unroll
    for (int i = 0; i < NP; ++i) {
        int h0 = k * HPJ + 2 * i;
        v2f bb;
        bb.x = (h0     < HH) ? b1[h0]     : 0.f;
        bb.y = (h0 + 1 < HH) ? b1[h0 + 1] : 0.f;
        c1[i] = acc[i] + bb;
    }
    // bias neuron: pad slot h=55 (k=3, pair 6, .y) fires every step (m: 2 -> 10, >1),
    // its W2 column is b2 -> cur2 arrives with bias already included (all 5 classes).
    if (k == 3) c1[6].y = 2.0f;

    // W2 fragments (70 VGPRs). FETCH_SIZE across rounds proves these load once.
    v2f w2r[NC][NP];
#pragma unroll
    for (int c = 0; c < NC; ++c)
#pragma unroll
        for (int i = 0; i < NP; ++i) {
            int h0 = k * HPJ + 2 * i;
            w2r[c][i].x = (h0     < HH) ? W2[c * HH + h0]     : 0.f;
            w2r[c][i].y = (h0 + 1 < HH) ? W2[c * HH + h0 + 1] : 0.f;
        }
    if (k == 3) {
#pragma unroll
        for (int c = 0; c < NC; ++c) w2r[c][6].y = b2[c];
    }

    // ---------------- Phase 2: 100-step LIF recurrence (software-pipelined) -----
    v2f m1[NP], s1[NP];
#pragma unroll
    for (int i = 0; i < NP; ++i) { m1[i] = (v2f){0.f, 0.f}; s1[i] = (v2f){0.f, 0.f}; }
    float mA = 0.f, sA = 0.f, mB = 0.f, sB = 0.f;

    const size_t stride = (size_t)Brows * NC;
    float* spkBase = out;                          // + t*stride each step (wave-uniform)
    float* memBase = out + (size_t)NS * stride;
    const int offA = row * NC + k;                 // lanes k=0..3 -> 4 consecutive dwords
    const int offB = row * NC + 4;

    v2f cp[NC];
    // layer-1 step: advance m1/s1 one step and produce fresh class partials cp.
    // Packed: per pair = 3 pk_fma + 2 med3 + 5 pk_fma (identical arithmetic order
    // and rounding to the scalar version: t0-s1 via pk_fma(s1,-1,t0) is exact for
    // s1 in {0,1}; med3(t,0,1) == min(max(t,0),1) for finite t).
    auto S1 = [&]() {
#pragma unroll
        for (int c = 0; c < NC; ++c) cp[c] = ZERO2;
#pragma unroll
        for (int i = 0; i < NP; ++i) {
            v2f t0 = pk_fma(BETA2, m1[i], c1[i]);     // beta*m1 + c1
            v2f m  = pk_fma(s1[i], MONE2, t0);        // ... - s1 (exact)
            m1[i] = m;
            v2f t1 = pk_fma(m, BIG2, NBIG2);          // (m-1)*2^60
            v2f s;
            s.x = __builtin_amdgcn_fmed3f(t1.x, 0.f, 1.f);
            s.y = __builtin_amdgcn_fmed3f(t1.y, 0.f, 1.f);
            s1[i] = s;
#pragma unroll
            for (int c = 0; c < NC; ++c)
                cp[c] = pk_fma(s, w2r[c][i], cp[c]);
        }
    };

    // one full timestep: reduce current cp (step t), pipeline S1 for t+1, layer-2 + store
    auto STEP = [&]() {
        float cur2[NC];
#pragma unroll
        for (int c = 0; c < NC; ++c) {
            float r = cp[c].x + cp[c].y;
            r += dpp_xor1(r);
            r += dpp_xor2(r);
            cur2[c] = r;
        }
        // layer-1 of next step — independent of cur2; fills DPP hazard slots and
        // the serial layer-2 chain below. (extra run on the last step touches no
        // memory; harmless)
        S1();

        float cA = (k == 1) ? cur2[1] : (k == 2) ? cur2[2] :
                   (k == 3) ? cur2[3] : cur2[0];
        float cB = cur2[4];

        mA = fmaf(BETA, mA, cA) - sA;   // b2 folded in via bias neuron
        sA = spike1(mA);
        mB = fmaf(BETA, mB, cB) - sB;
        sB = spike1(mB);

        spkBase[offA] = sA;                   // 4 consecutive dwords per quad
        memBase[offA] = mA;
        if (k == 0) { spkBase[offB] = sB; memBase[offB] = mB; }

        spkBase += stride;
        memBase += stride;
    };

    S1();   // cp for t = 0
    int t = 0;
    for (; t + 2 <= NS; t += 2) {   // manual 2x unroll: store temps get a full
        STEP();                     // iteration of rename distance
        STEP();
    }
    if (t < NS) STEP();
}

extern "C" void kernel_launch(void* const* d_in, const int* in_sizes, int n_in,
                              void* d_out, int out_size, void* d_ws, size_t ws_size,
                              hipStream_t stream) {
    const float* x  = (const float*)d_in[0];
    const float* W1 = (const float*)d_in[1];
    const float* b1 = (const float*)d_in[2];
    const float* W2 = (const float*)d_in[3];
    const float* b2 = (const float*)d_in[4];
    const int*   ns = (const int*)d_in[5];
    int B = in_sizes[0] / DD;          // 32768
    int nblocks = B / RPB;             // 512 -> 2 blocks/CU, 8 waves/CU
    snn_kernel<<<nblocks, BLK, 0, stream>>>(x, W1, b1, W2, b2, ns, (float*)d_out, B);
}

// Round 6
// 226.918 us; speedup vs baseline: 1.0222x; 1.0222x over previous
//
#include <hip/hip_runtime.h>

typedef float v2f __attribute__((ext_vector_type(2)));
typedef float v4f __attribute__((ext_vector_type(4)));

#define DD   187   // input dim
#define HH   50    // hidden
#define PH   64    // LDS padded hidden (4 lanes x 16 slots)
#define HPJ  14    // hidden neurons per lane (logical)
#define HPL  16    // LDS slots per lane (64B -> b128-aligned reads)
#define NP   7     // float2 pairs per lane
#define NC   5     // classes
#define RPB  64    // rows per block (4 lanes/row, 256 threads)
#define BLK  256
#define DCH  64    // d-chunk
#define NCHUNK 3   // ceil(187/64)
#define XSS  68    // xs row stride (mult of 4 -> 16B-aligned v4f reads)
#define BETA 0.9f
#define TILE 4     // steps buffered in LDS between flushes
#define SLAB 320   // dwords per (tile-step, array) slab = RPB*NC

__device__ __forceinline__ float dpp_xor1(float v) {
    // quad_perm [1,0,3,2] -> lane^1
    return __builtin_bit_cast(float,
        __builtin_amdgcn_mov_dpp(__builtin_bit_cast(int, v), 0xB1, 0xF, 0xF, true));
}
__device__ __forceinline__ float dpp_xor2(float v) {
    // quad_perm [2,3,0,1] -> lane^2
    return __builtin_bit_cast(float,
        __builtin_amdgcn_mov_dpp(__builtin_bit_cast(int, v), 0x4E, 0xF, 0xF, true));
}

__device__ __forceinline__ float spike1(float m) {
    // exact (m > 1) ? 1 : 0 : fma(m,2^60,-2^60) > 0 iff m>1 (f32), med3-clamp [0,1]
    // (med3 variant validated bit-exact in round 5: absmax identical)
    float t = fmaf(m, 0x1.0p60f, -0x1.0p60f);
    return __builtin_amdgcn_fmed3f(t, 0.f, 1.f);
}
__device__ __forceinline__ v2f spike2(v2f m) {
    const v2f BIG2  = { 0x1.0p60f,  0x1.0p60f};
    const v2f NBIG2 = {-0x1.0p60f, -0x1.0p60f};
    v2f t = __builtin_elementwise_fma(m, BIG2, NBIG2);
    v2f s;
    s.x = __builtin_amdgcn_fmed3f(t.x, 0.f, 1.f);
    s.y = __builtin_amdgcn_fmed3f(t.y, 0.f, 1.f);
    return s;
}

__device__ __forceinline__ v2f vlo(v4f v) { return __builtin_shufflevector(v, v, 0, 1); }
__device__ __forceinline__ v2f vhi(v4f v) { return __builtin_shufflevector(v, v, 2, 3); }

// Structural occupancy is 2 waves/SIMD (2048 waves / 1024 SIMDs).
__global__ __launch_bounds__(BLK, 2) __attribute__((amdgpu_waves_per_eu(2, 2)))
void snn_kernel(const float* __restrict__ x,
                const float* __restrict__ W1,
                const float* __restrict__ b1,
                const float* __restrict__ W2,
                const float* __restrict__ b2,
                const int*   __restrict__ nsp,
                float* __restrict__ out, int Brows)
{
    // one shared pool: phase 1 carves xs+w1t; phase 2 reuses it (after the final
    // phase-1 barrier) as a double-buffered output staging area:
    //   obuf[buf][tl][arr] = SLAB dwords, buf in {0,1}, tl in [0,TILE), arr in {spk,mem}
    __shared__ __align__(16) float smem[RPB * XSS + DCH * PH];   // 33,792 B
    float* xs  = smem;                 // RPB*XSS = 4352 floats
    float* w1t = smem + RPB * XSS;     // DCH*PH  = 4096 floats
    // phase-2 staging needs 2*TILE*2*SLAB = 5120 floats (20,480 B) -> fits in smem

    const int tid = threadIdx.x;
    const int p   = tid >> 2;         // row within block (quad id)
    const int k   = tid & 3;          // lane within quad: hidden slice + class owner
    const int row = blockIdx.x * RPB + p;
    const int NS  = nsp[0];

    // ---------------- Phase 1: cur1 = x @ W1^T (chunked over d) ----------------
    v2f acc[NP];
#pragma unroll
    for (int i = 0; i < NP; ++i) acc[i] = (v2f){0.f, 0.f};

    for (int ch = 0; ch < NCHUNK; ++ch) {
        const int d0 = ch * DCH;
        for (int i = tid; i < RPB * DCH; i += BLK) {
            int r = i >> 6, dd = i & 63;
            int d = d0 + dd;
            xs[r * XSS + dd] = (d < DD) ? x[(size_t)(blockIdx.x * RPB + r) * DD + d] : 0.f;
        }
        // conflict-free staging: consecutive threads -> consecutive LDS addresses.
        // slot s = kk*16 + j holds logical hidden h = kk*14 + j (j<14), pads zero.
        for (int i = tid; i < DCH * PH; i += BLK) {
            int dd = i >> 6, s = i & 63;
            int kk = s >> 4, j = s & 15;
            int h = kk * HPJ + j;
            int d = d0 + dd;
            w1t[dd * PH + s] = (j < HPJ && h < HH && d < DD) ? W1[h * DD + d] : 0.f;
        }
        __syncthreads();

        const float* xr = xs + p * XSS;
#pragma unroll 2
        for (int d4 = 0; d4 < DCH / 4; ++d4) {
            v4f xv4 = *(const v4f*)(xr + 4 * d4);
#pragma unroll
            for (int j = 0; j < 4; ++j) {
                int d = 4 * d4 + j;
                const float* wbase = w1t + d * PH + k * HPL;   // 64B aligned per lane
                v4f w0 = *(const v4f*)(wbase);
                v4f w1v = *(const v4f*)(wbase + 4);
                v4f w2v = *(const v4f*)(wbase + 8);
                v2f w3 = *(const v2f*)(wbase + 12);            // pairs (12,13)
                float xv = xv4[j];
                v2f xvv = {xv, xv};
                acc[0] = __builtin_elementwise_fma(xvv, vlo(w0),  acc[0]);
                acc[1] = __builtin_elementwise_fma(xvv, vhi(w0),  acc[1]);
                acc[2] = __builtin_elementwise_fma(xvv, vlo(w1v), acc[2]);
                acc[3] = __builtin_elementwise_fma(xvv, vhi(w1v), acc[3]);
                acc[4] = __builtin_elementwise_fma(xvv, vlo(w2v), acc[4]);
                acc[5] = __builtin_elementwise_fma(xvv, vhi(w2v), acc[5]);
                acc[6] = __builtin_elementwise_fma(xvv, w3,       acc[6]);
            }
        }
        __syncthreads();   // after this, xs/w1t are dead -> smem reusable for obuf
    }

    // cur1 = acc + b1 (pads stay 0 -> padded neurons never spike)
    v2f c1[NP];
#pragma unroll
    for (int i = 0; i < NP; ++i) {
        int h0 = k * HPJ + 2 * i;
        v2f bb;
        bb.x = (h0     < HH) ? b1[h0]     : 0.f;
        bb.y = (h0 + 1 < HH) ? b1[h0 + 1] : 0.f;
        c1[i] = acc[i] + bb;
    }
    // bias neuron: pad slot h=55 (k=3, pair 6, .y) fires every step (m: 2 -> 10, >1),
    // its W2 column is b2 -> cur2 arrives with bias already included (all 5 classes).
    if (k == 3) c1[6].y = 2.0f;

    // W2 fragments (70 VGPRs). FETCH_SIZE across rounds proves these load once.
    v2f w2r[NC][NP];
#pragma unroll
    for (int c = 0; c < NC; ++c)
#pragma unroll
        for (int i = 0; i < NP; ++i) {
            int h0 = k * HPJ + 2 * i;
            w2r[c][i].x = (h0     < HH) ? W2[c * HH + h0]     : 0.f;
            w2r[c][i].y = (h0 + 1 < HH) ? W2[c * HH + h0 + 1] : 0.f;
        }
    if (k == 3) {
#pragma unroll
        for (int c = 0; c < NC; ++c) w2r[c][6].y = b2[c];
    }

    // keep w2r/c1 opaque (no in-loop remat) — neutral in r3, retained for stability
#pragma unroll
    for (int c = 0; c < NC; ++c) {
        asm volatile("" : "+v"(w2r[c][0]), "+v"(w2r[c][1]), "+v"(w2r[c][2]),
                          "+v"(w2r[c][3]), "+v"(w2r[c][4]), "+v"(w2r[c][5]),
                          "+v"(w2r[c][6]));
    }
    asm volatile("" : "+v"(c1[0]), "+v"(c1[1]), "+v"(c1[2]), "+v"(c1[3]),
                      "+v"(c1[4]), "+v"(c1[5]), "+v"(c1[6]));

    // ---------------- Phase 2: 100-step LIF recurrence ----------------
    // STORE-PATH ABLATION: rounds 0-5 held dur at ~107-118us regardless of
    // instruction count (r5: -40% instr, +10% time) -> latency/stall-bound with
    // ~1400 idle cyc/step unexplained by VALU chains. The only never-varied
    // in-loop structure is the 4 scattered+divergent global stores per wave per
    // step. This round: results -> LDS (ds_write), flush every TILE steps as
    // wide coalesced dwordx2 stores, double-buffered so flush stores retire
    // under the next tile's compute.
    v2f m1[NP], s1[NP];
#pragma unroll
    for (int i = 0; i < NP; ++i) { m1[i] = (v2f){0.f, 0.f}; s1[i] = (v2f){0.f, 0.f}; }
    float mA = 0.f, sA = 0.f, mB = 0.f, sB = 0.f;

    const size_t stride = (size_t)Brows * NC;
    const size_t rowBase5 = (size_t)blockIdx.x * RPB * NC;
    float* spkT = out;                         // start of current tile's spk slab
    float* memT = out + (size_t)NS * stride;   // start of current tile's mem slab
    const int q5  = p * NC;
    const int q5k = q5 + k;
    const v2f BETA2 = {BETA, BETA};
    const v2f ZERO2 = {0.f, 0.f};

    v2f cp[NC];
    // layer-1 step: advance m1/s1 one step and produce fresh class partials cp
    auto S1 = [&]() {
#pragma unroll
        for (int c = 0; c < NC; ++c) cp[c] = ZERO2;
#pragma unroll
        for (int i = 0; i < NP; ++i) {
            v2f m = __builtin_elementwise_fma(BETA2, m1[i], c1[i]) - s1[i];
            m1[i] = m;
            v2f s = spike2(m);
            s1[i] = s;
#pragma unroll
            for (int c = 0; c < NC; ++c)
                cp[c] = __builtin_elementwise_fma(s, w2r[c][i], cp[c]);
        }
    };

    // one timestep: reduce cp (step t), pipeline S1 for t+1, layer-2, LDS write
    auto STEP_T = [&](int bi, int tl) {
        float cur2[NC];
#pragma unroll
        for (int c = 0; c < NC; ++c) {
            float r = cp[c].x + cp[c].y;
            r += dpp_xor1(r);
            r += dpp_xor2(r);
            cur2[c] = r;
        }
        S1();   // next step's layer-1, independent of cur2 (fills stall slots)

        float cA = (k == 1) ? cur2[1] : (k == 2) ? cur2[2] :
                   (k == 3) ? cur2[3] : cur2[0];
        float cB = cur2[4];

        mA = fmaf(BETA, mA, cA) - sA;   // b2 folded in via bias neuron
        sA = spike1(mA);
        mB = fmaf(BETA, mB, cB) - sB;
        sB = spike1(mB);

        float* sb = smem + ((bi * TILE + tl) * 2 + 0) * SLAB;
        float* mb = smem + ((bi * TILE + tl) * 2 + 1) * SLAB;
        sb[q5k] = sA;
        mb[q5k] = mA;
        if (k == 0) { sb[q5 + 4] = sB; mb[q5 + 4] = mB; }
    };

    // flush cnt buffered steps of buffer bi as coalesced 8B stores.
    // 2*cnt slabs x 160 float2-units; thread handles up to 5 units.
    auto FLUSH = [&](int bi, int cnt, float* spkB, float* memB) {
        const int total = cnt * SLAB;              // float2-units = cnt*320
#pragma unroll
        for (int u = 0; u < 2 * TILE * SLAB / (2 * BLK); ++u) {   // 5
            int idx = u * BLK + tid;
            if (idx < total) {
                int slab = idx / 160;              // 0 .. 2*cnt-1
                int pos  = idx - slab * 160;       // float2 within slab
                int tl2  = slab >> 1;
                int arr  = slab & 1;
                v2f val = *(const v2f*)(smem +
                          (((bi * TILE + tl2) * 2 + arr) * SLAB + pos * 2));
                float* gb = (arr ? memB : spkB) + (size_t)tl2 * stride
                            + rowBase5 + (size_t)(pos * 2);
                *(v2f*)gb = val;
            }
        }
    };

    S1();   // cp for t = 0
    int t = 0, bi = 0;
    for (; t + TILE <= NS; t += TILE) {
        STEP_T(bi, 0); STEP_T(bi, 1); STEP_T(bi, 2); STEP_T(bi, 3);
        __syncthreads();                  // buffer bi complete, safe to read
        FLUSH(bi, TILE, spkT, memT);      // stores retire under next tile's compute
        spkT += (size_t)TILE * stride;
        memT += (size_t)TILE * stride;
        bi ^= 1;
    }
    int rem = NS - t;
    if (rem > 0) {
        for (int tl = 0; tl < rem; ++tl) STEP_T(bi, tl);
        __syncthreads();
        FLUSH(bi, rem, spkT, memT);
    }
}

extern "C" void kernel_launch(void* const* d_in, const int* in_sizes, int n_in,
                              void* d_out, int out_size, void* d_ws, size_t ws_size,
                              hipStream_t stream) {
    const float* x  = (const float*)d_in[0];
    const float* W1 = (const float*)d_in[1];
    const float* b1 = (const float*)d_in[2];
    const float* W2 = (const float*)d_in[3];
    const float* b2 = (const float*)d_in[4];
    const int*   ns = (const int*)d_in[5];
    int B = in_sizes[0] / DD;          // 32768
    int nblocks = B / RPB;             // 512 -> 2 blocks/CU, 8 waves/CU
    snn_kernel<<<nblocks, BLK, 0, stream>>>(x, W1, b1, W2, b2, ns, (float*)d_out, B);
}